// Round 14
// baseline (537.654 us; speedup 1.0000x reference)
//
#include <hip/hip_runtime.h>

#define LEAK 0.1f
#define BN_EPS 1e-5f

constexpr int N_NODES = 100000;
constexpr int N_EDGES = 2000000;
constexpr int N_NF = 16;
constexpr int N_EF = 19;
constexpr int D0 = 2 * N_NF + N_EF;  // 51
constexpr int D1 = 64, D2 = 64, D3 = 32, D4 = 16, D5 = 8, D6 = 2;

// ws layout (in floats)
constexpr int OFF_E_SUM = 0;
constexpr int OFF_E_SQ  = 32;
constexpr int OFF_X_SUM = 64;
constexpr int OFF_X_SQ  = 96;
constexpr int OFF_W1P   = 256;                // 51*64 folded W1
constexpr int OFF_B1P   = OFF_W1P + D0 * D1;  // 64 folded b1

typedef __attribute__((ext_vector_type(8))) short short8;   // bf16x8 MFMA A/B frag
typedef __attribute__((ext_vector_type(4))) short short4v;  // 8B LDS write
typedef __attribute__((ext_vector_type(4))) float f32x4;    // MFMA C/D frag

// float -> bf16 bits, RNE (inputs finite)
static __device__ __forceinline__ short f2bf(float f) {
  unsigned u = __builtin_bit_cast(unsigned, f);
  unsigned r = (u + 0x7FFFu + ((u >> 16) & 1u)) >> 16;
  return (short)r;
}

// ---------------- e column stats: LDS-staged, coalesced ----------------
constexpr int SROWS = 256;
__global__ __launch_bounds__(256) void e_stats_kernel(const float* __restrict__ v,
                                                      float* __restrict__ acc_sum,
                                                      float* __restrict__ acc_sq) {
  __shared__ float lbuf[SROWS * N_EF];  // 4864 floats
  const int t = threadIdx.x;
  float s = 0.f, qq = 0.f;
  const int col = t % N_EF;
  const int rep = t / N_EF;  // rep<13 for t<247
  const int nchunks = (N_EDGES + SROWS - 1) / SROWS;
  for (int c = blockIdx.x; c < nchunks; c += gridDim.x) {
    const int nr = min(SROWS, N_EDGES - c * SROWS);
    const int nf4 = nr * N_EF / 4;  // nr is 256 or 128 -> divisible
    const float4* src = (const float4*)(v + (size_t)c * SROWS * N_EF);
    for (int i = t; i < nf4; i += 256) ((float4*)lbuf)[i] = src[i];
    __syncthreads();
    if (rep < 13) {
      for (int r = rep; r < nr; r += 13) {
        float x = lbuf[r * N_EF + col];
        s += x; qq += x * x;
      }
    }
    __syncthreads();
  }
  lbuf[t] = s; lbuf[256 + t] = qq;
  __syncthreads();
  if (t < N_EF) {
    float ts = 0.f, tq = 0.f;
#pragma unroll
    for (int rp = 0; rp < 13; rp++) {
      ts += lbuf[t + N_EF * rp];
      tq += lbuf[256 + t + N_EF * rp];
    }
    atomicAdd(&acc_sum[t], ts);
    atomicAdd(&acc_sq[t], tq);
  }
}

// ---------------- x column stats (6.4MB, cheap) ----------------
template <int NF>
__global__ void col_stats_kernel(const float* __restrict__ v, int nrows,
                                 float* __restrict__ acc_sum,
                                 float* __restrict__ acc_sq) {
  float s[NF], qq[NF];
#pragma unroll
  for (int k = 0; k < NF; k++) { s[k] = 0.f; qq[k] = 0.f; }
  int tid = blockIdx.x * blockDim.x + threadIdx.x;
  int stride = gridDim.x * blockDim.x;
  for (int r = tid; r < nrows; r += stride) {
    const float* __restrict__ row = v + (size_t)r * NF;
#pragma unroll
    for (int k = 0; k < NF; k++) { float t = row[k]; s[k] += t; qq[k] += t * t; }
  }
#pragma unroll
  for (int k = 0; k < NF; k++) {
#pragma unroll
    for (int off = 32; off > 0; off >>= 1) {
      s[k] += __shfl_down(s[k], off);
      qq[k] += __shfl_down(qq[k], off);
    }
  }
  __shared__ float ls[4][2 * NF];
  int wave = threadIdx.x >> 6;
  int lane = threadIdx.x & 63;
  if (lane == 0) {
#pragma unroll
    for (int k = 0; k < NF; k++) { ls[wave][k] = s[k]; ls[wave][NF + k] = qq[k]; }
  }
  __syncthreads();
  if (threadIdx.x < 2 * NF) {
    float t = ls[0][threadIdx.x] + ls[1][threadIdx.x] + ls[2][threadIdx.x] +
              ls[3][threadIdx.x];
    if (threadIdx.x < NF) atomicAdd(&acc_sum[threadIdx.x], t);
    else                  atomicAdd(&acc_sq[threadIdx.x - NF], t);
  }
}

// ---------------- fold BN into W1/b1 ----------------
__global__ void fold_bn_kernel(const float* __restrict__ ws,
                               const float* __restrict__ ng, const float* __restrict__ nb,
                               const float* __restrict__ eg, const float* __restrict__ eb,
                               const float* __restrict__ W1, const float* __restrict__ b1,
                               float* __restrict__ W1p, float* __restrict__ b1p) {
  __shared__ float sc[D0], sh[D0];
  int t = threadIdx.x;  // 64 threads
  if (t < D0) {
    float mean, var, g, b;
    if (t < 2 * N_NF) {
      int k = t & (N_NF - 1);
      mean = ws[OFF_X_SUM + k] / (float)N_NODES;
      var  = ws[OFF_X_SQ + k] / (float)N_NODES - mean * mean;
      g = ng[k]; b = nb[k];
    } else {
      int k = t - 2 * N_NF;
      mean = ws[OFF_E_SUM + k] / (float)N_EDGES;
      var  = ws[OFF_E_SQ + k] / (float)N_EDGES - mean * mean;
      g = eg[k]; b = eb[k];
    }
    float scale = g / sqrtf(var + BN_EPS);
    sc[t] = scale;
    sh[t] = b - mean * scale;
  }
  __syncthreads();
  if (t < D1) {
    float accb = b1[t];
    for (int i = 0; i < D0; i++) {
      float w = W1[i * D1 + t];
      W1p[i * D1 + t] = w * sc[i];
      accb += sh[i] * w;
    }
    b1p[t] = accb;
  }
}

// ---------------- MFMA edge MLP (M=32/wave, ei+e prefetch, no spill) --------
// Wave-private LDS tile: 32 edge-rows x 64 bf16 cols (128B stride), XOR swizzle
// ((row&7)<<4). Two independent 16-row MFMA chains share W frags (2x ILP).
// Prefetch across iterations: ONLY ei indices (4 VGPR) + e rows (14 VGPR) --
// the x gather is L2/L3-hot and demand-loaded (round-12 lesson: full Pref
// prefetch spilled at VGPR=128 -> 85MB scratch writes).

__device__ __forceinline__ short8 load_wfrag(const float* __restrict__ W, int ldn,
                                             int kbase, int nbase, int kmax, int nmax,
                                             int q, int g) {
  short8 f;
#pragma unroll
  for (int j = 0; j < 8; j++) {
    int k = kbase + g * 8 + j;
    int n = nbase + q;
    float w = (k < kmax && n < nmax) ? W[k * ldn + n] : 0.f;
    f[j] = f2bf(w);
  }
  return f;
}

__device__ __forceinline__ void load_e7(const float* __restrict__ er, int g,
                                        float (&o)[7]) {
  o[0] = er[g * 4 + 0]; o[1] = er[g * 4 + 1];
  o[2] = er[g * 4 + 2]; o[3] = er[g * 4 + 3];
  if (g == 0) { o[4] = er[16]; o[5] = er[17]; o[6] = er[18]; }
  else        { o[4] = 0.f; o[5] = 0.f; o[6] = 0.f; }
}

__device__ __forceinline__ void stage_row2(char* lb, int row, int swzq, int g,
                                           float4 vs, float4 vd, const float (&ev)[7]) {
  char* base = lb + row * 128;
  short4v ps = {f2bf(vs.x), f2bf(vs.y), f2bf(vs.z), f2bf(vs.w)};
  *(short4v*)(base + ((g * 8) ^ swzq)) = ps;
  short4v pd = {f2bf(vd.x), f2bf(vd.y), f2bf(vd.z), f2bf(vd.w)};
  *(short4v*)(base + ((32 + g * 8) ^ swzq)) = pd;
  short4v pe = {f2bf(ev[0]), f2bf(ev[1]), f2bf(ev[2]), f2bf(ev[3])};
  *(short4v*)(base + ((64 + g * 8) ^ swzq)) = pe;
  short4v pt = {f2bf(ev[4]), f2bf(ev[5]), f2bf(ev[6]), 0};  // all bytes defined
  *(short4v*)(base + ((96 + g * 8) ^ swzq)) = pt;
}

template <int KT, int NT>
__device__ __forceinline__ void mfma_layer2(char* lb, int q, int g, int swzq,
                                            const short8 (&wf)[KT][NT],
                                            const float (&bv)[NT]) {
  short8 a0[KT], a1[KT];
#pragma unroll
  for (int kk = 0; kk < KT; kk++) {
    a0[kk] = *(const short8*)(lb + q * 128 + ((kk * 64 + g * 16) ^ swzq));
    a1[kk] = *(const short8*)(lb + (q + 16) * 128 + ((kk * 64 + g * 16) ^ swzq));
  }
  f32x4 acc0[NT], acc1[NT];
#pragma unroll
  for (int nt = 0; nt < NT; nt++) {
    acc0[nt] = (f32x4){bv[nt], bv[nt], bv[nt], bv[nt]};
    acc1[nt] = acc0[nt];
#pragma unroll
    for (int kk = 0; kk < KT; kk++) {
      acc0[nt] = __builtin_amdgcn_mfma_f32_16x16x32_bf16(a0[kk], wf[kk][nt], acc0[nt], 0, 0, 0);
      acc1[nt] = __builtin_amdgcn_mfma_f32_16x16x32_bf16(a1[kk], wf[kk][nt], acc1[nt], 0, 0, 0);
    }
  }
#pragma unroll
  for (int nt = 0; nt < NT; nt++) {
#pragma unroll
    for (int r = 0; r < 4; r++) {
      float v0 = acc0[nt][r];
      v0 = fmaxf(v0, LEAK * v0);
      int mw0 = 4 * g + r;
      *(short*)(lb + mw0 * 128 + ((nt * 32 + q * 2) ^ ((mw0 & 7) << 4))) = f2bf(v0);
      float v1 = acc1[nt][r];
      v1 = fmaxf(v1, LEAK * v1);
      int mw1 = 16 + 4 * g + r;
      *(short*)(lb + mw1 * 128 + ((nt * 32 + q * 2) ^ ((mw1 & 7) << 4))) = f2bf(v1);
    }
  }
}

#define RED16(v)                 \
  v += __shfl_xor(v, 1);         \
  v += __shfl_xor(v, 2);         \
  v += __shfl_xor(v, 4);         \
  v += __shfl_xor(v, 8);

__device__ __forceinline__ void tail56(char* lb, int roff, int q, int g, int swzq,
                                       short8 w5f, float b5v, float w60, float w61,
                                       float b60, float b61, float* out, int Eb) {
  short8 a5 = *(const short8*)(lb + (q + roff) * 128 + ((g * 16) ^ swzq));
  f32x4 acc5 = (f32x4){b5v, b5v, b5v, b5v};
  acc5 = __builtin_amdgcn_mfma_f32_16x16x32_bf16(a5, w5f, acc5, 0, 0, 0);
  float a50 = fmaxf(acc5[0], LEAK * acc5[0]);
  float a51 = fmaxf(acc5[1], LEAK * acc5[1]);
  float a52 = fmaxf(acc5[2], LEAK * acc5[2]);
  float a53 = fmaxf(acc5[3], LEAK * acc5[3]);
  float s00 = a50 * w60, s10 = a50 * w61;
  float s01 = a51 * w60, s11 = a51 * w61;
  float s02 = a52 * w60, s12 = a52 * w61;
  float s03 = a53 * w60, s13 = a53 * w61;
  RED16(s00) RED16(s10) RED16(s01) RED16(s11)
  RED16(s02) RED16(s12) RED16(s03) RED16(s13)
  if (q < 4) {
    float o0 = (q == 0) ? s00 : (q == 1) ? s01 : (q == 2) ? s02 : s03;
    float o1 = (q == 0) ? s10 : (q == 1) ? s11 : (q == 2) ? s12 : s13;
    ((float2*)out)[(size_t)Eb + roff + g * 4 + q] = make_float2(o0 + b60, o1 + b61);
  }
}

__global__ __launch_bounds__(256) void edge_mlp_mfma_kernel(
    const float* __restrict__ x, const float* __restrict__ e,
    const int* __restrict__ ei,
    const float* __restrict__ W1p, const float* __restrict__ b1p,
    const float* __restrict__ W2, const float* __restrict__ b2,
    const float* __restrict__ W3, const float* __restrict__ b3,
    const float* __restrict__ W4, const float* __restrict__ b4,
    const float* __restrict__ W5, const float* __restrict__ b5,
    const float* __restrict__ W6, const float* __restrict__ b6,
    float* __restrict__ out) {
  __shared__ __align__(16) char actbuf[4 * 32 * 128];  // 4 waves x 4KB (single buf)

  const int lane = threadIdx.x & 63;
  const int wave = threadIdx.x >> 6;
  const int q = lane & 15;
  const int g = lane >> 4;
  const int swzq = (q & 7) << 4;
  char* lb = actbuf + wave * 4096;

  // ---- weights -> per-lane register fragments (once per block) ----
  short8 w1f[2][4], w2f[2][4], w3f[2][2], w4f[1][1];
  float b1v[4], b2v[4], b3v[2], b4v[1];
#pragma unroll
  for (int kk = 0; kk < 2; kk++)
#pragma unroll
    for (int nt = 0; nt < 4; nt++) {
      w1f[kk][nt] = load_wfrag(W1p, 64, kk * 32, nt * 16, D0, 64, q, g);
      w2f[kk][nt] = load_wfrag(W2, 64, kk * 32, nt * 16, 64, 64, q, g);
    }
#pragma unroll
  for (int kk = 0; kk < 2; kk++)
#pragma unroll
    for (int nt = 0; nt < 2; nt++)
      w3f[kk][nt] = load_wfrag(W3, 32, kk * 32, nt * 16, 64, 32, q, g);
  w4f[0][0] = load_wfrag(W4, 16, 0, 0, 32, 16, q, g);
  short8 w5f = load_wfrag(W5, 8, 0, 0, 16, 8, q, g);
#pragma unroll
  for (int nt = 0; nt < 4; nt++) { b1v[nt] = b1p[nt * 16 + q]; b2v[nt] = b2[nt * 16 + q]; }
#pragma unroll
  for (int nt = 0; nt < 2; nt++) b3v[nt] = b3[nt * 16 + q];
  b4v[0] = b4[q];
  float b5v = (q < 8) ? b5[q] : 0.f;
  float w60 = (q < 8) ? W6[q * 2 + 0] : 0.f;
  float w61 = (q < 8) ? W6[q * 2 + 1] : 0.f;
  float b60 = b6[0], b61 = b6[1];

  const int n_bt = N_EDGES / 128;  // 15625 block-tiles of 128 edges
  int bt = blockIdx.x;
  int s1 = 0, d1 = 0, s2 = 0, d2 = 0;
  float e1[7] = {0, 0, 0, 0, 0, 0, 0}, e2[7] = {0, 0, 0, 0, 0, 0, 0};
  if (bt < n_bt) {
    const int Eb0 = bt * 128 + wave * 32;
    s1 = ei[Eb0 + q];      d1 = ei[N_EDGES + Eb0 + q];
    s2 = ei[Eb0 + 16 + q]; d2 = ei[N_EDGES + Eb0 + 16 + q];
    load_e7(e + (size_t)(Eb0 + q) * N_EF, g, e1);
    load_e7(e + (size_t)(Eb0 + 16 + q) * N_EF, g, e2);
  }
  for (; bt < n_bt; bt += gridDim.x) {
    const int Eb = bt * 128 + wave * 32;
    // ---- demand x gathers for current tile (L2/L3-hot; issue first) ----
    float4 vs1 = ((const float4*)x)[(size_t)s1 * 4 + g];
    float4 vd1 = ((const float4*)x)[(size_t)d1 * 4 + g];
    float4 vs2 = ((const float4*)x)[(size_t)s2 * 4 + g];
    float4 vd2 = ((const float4*)x)[(size_t)d2 * 4 + g];
    // ---- prefetch next tile's ei + e rows (hidden under this tile) ----
    const int nbt = bt + gridDim.x;
    int ns1 = s1, nd1 = d1, ns2 = s2, nd2 = d2;
    float f1[7], f2[7];
#pragma unroll
    for (int i = 0; i < 7; i++) { f1[i] = e1[i]; f2[i] = e2[i]; }
    if (nbt < n_bt) {
      const int nEb = nbt * 128 + wave * 32;
      ns1 = ei[nEb + q];      nd1 = ei[N_EDGES + nEb + q];
      ns2 = ei[nEb + 16 + q]; nd2 = ei[N_EDGES + nEb + 16 + q];
      load_e7(e + (size_t)(nEb + q) * N_EF, g, f1);
      load_e7(e + (size_t)(nEb + 16 + q) * N_EF, g, f2);
    }
    // ---- stage rows q and q+16 ----
    stage_row2(lb, q, swzq, g, vs1, vd1, e1);
    stage_row2(lb, q + 16, swzq, g, vs2, vd2, e2);
    // ---- layers 1-4 (two 16-row chains interleaved) ----
    mfma_layer2<2, 4>(lb, q, g, swzq, w1f, b1v);
    mfma_layer2<2, 4>(lb, q, g, swzq, w2f, b2v);
    mfma_layer2<2, 2>(lb, q, g, swzq, w3f, b3v);
    mfma_layer2<1, 1>(lb, q, g, swzq, w4f, b4v);
    // ---- layers 5+6 per sub-tile ----
    tail56(lb, 0,  q, g, swzq, w5f, b5v, w60, w61, b60, b61, out, Eb);
    tail56(lb, 16, q, g, swzq, w5f, b5v, w60, w61, b60, b61, out, Eb);
    // ---- rotate prefetch ----
    s1 = ns1; d1 = nd1; s2 = ns2; d2 = nd2;
#pragma unroll
    for (int i = 0; i < 7; i++) { e1[i] = f1[i]; e2[i] = f2[i]; }
  }
}

// ---------------- launch ----------------
extern "C" void kernel_launch(void* const* d_in, const int* in_sizes, int n_in,
                              void* d_out, int out_size, void* d_ws, size_t ws_size,
                              hipStream_t stream) {
  const float* x  = (const float*)d_in[0];
  const float* e  = (const float*)d_in[1];
  const int*   ei = (const int*)d_in[2];
  const float* ng = (const float*)d_in[4];
  const float* nb = (const float*)d_in[5];
  const float* eg = (const float*)d_in[6];
  const float* eb = (const float*)d_in[7];
  const float* W1 = (const float*)d_in[8];
  const float* b1 = (const float*)d_in[9];
  const float* W2 = (const float*)d_in[10];
  const float* b2 = (const float*)d_in[11];
  const float* W3 = (const float*)d_in[12];
  const float* b3 = (const float*)d_in[13];
  const float* W4 = (const float*)d_in[14];
  const float* b4 = (const float*)d_in[15];
  const float* W5 = (const float*)d_in[16];
  const float* b5 = (const float*)d_in[17];
  const float* W6 = (const float*)d_in[18];
  const float* b6 = (const float*)d_in[19];
  float* out = (float*)d_out;
  float* ws  = (float*)d_ws;

  (void)hipMemsetAsync(ws, 0, 128 * sizeof(float), stream);

  e_stats_kernel<<<1024, 256, 0, stream>>>(e, ws + OFF_E_SUM, ws + OFF_E_SQ);
  col_stats_kernel<N_NF><<<128, 256, 0, stream>>>(x, N_NODES, ws + OFF_X_SUM, ws + OFF_X_SQ);
  fold_bn_kernel<<<1, 64, 0, stream>>>(ws, ng, nb, eg, eb, W1, b1,
                                       ws + OFF_W1P, ws + OFF_B1P);

  edge_mlp_mfma_kernel<<<1024, 256, 0, stream>>>(
      x, e, ei, ws + OFF_W1P, ws + OFF_B1P,
      W2, b2, W3, b3, W4, b4, W5, b5, W6, b6, out);
}